// Round 2
// baseline (321.805 us; speedup 1.0000x reference)
//
#include <hip/hip_runtime.h>
#include <hip/hip_bf16.h>

typedef unsigned short us;
typedef __attribute__((ext_vector_type(8))) __bf16 bf16x8;
typedef __attribute__((ext_vector_type(4))) float f32x4;

#define MFMA16(a, b, c) __builtin_amdgcn_mfma_f32_16x16x32_bf16(a, b, c, 0, 0, 0)

static __device__ __forceinline__ us f2bf(float f) {
  __hip_bfloat16 h = __float2bfloat16(f);
  return __builtin_bit_cast(us, h);
}

// async global->LDS, 16B per lane; LDS dest is wave-uniform base + lane*16
static __device__ __forceinline__ void gll16(const us* g, us* l) {
  __builtin_amdgcn_global_load_lds((const __attribute__((address_space(1))) void*)g,
                                   (__attribute__((address_space(3))) void*)l,
                                   16, 0, 0);
}

// ---------------------------------------------------------------- casts ----
__global__ void cast_kernel(const float* __restrict__ in, us* __restrict__ out, int n4) {
  int i = blockIdx.x * blockDim.x + threadIdx.x;
  if (i >= n4) return;
  float4 v = ((const float4*)in)[i];
  ushort4 o;
  o.x = f2bf(v.x); o.y = f2bf(v.y); o.z = f2bf(v.z); o.w = f2bf(v.w);
  ((ushort4*)out)[i] = o;
}

// -------------------------------------------------------------- rope tab ----
__global__ void rope_table_kernel(float* __restrict__ ct, float* __restrict__ st) {
  int t = blockIdx.x, d = threadIdx.x;
  float ang = (float)t * exp2f((float)d * -0.20762050593046014f);
  float s, c;
  sincosf(ang, &s, &c);
  ct[t * 64 + d] = c;
  st[t * 64 + d] = s;
}

// ------------------------------------------- GEMM1: qkv + RoPE + scatter ----
// A = xb [8192][1024], B = wqb [3072][1024] (out[m][n]=sum_k A[m,k]B[n,k])
// epilogue: which=by/8 (0=q,1=k,2=v), h=by%8; q/k roped -> [b][h][t][128]; v -> vT [b][h][128][4096]
__global__ __launch_bounds__(256, 2)
void qkv_rope_kernel(const us* __restrict__ A, const us* __restrict__ B,
                     const float* __restrict__ ctab, const float* __restrict__ stab,
                     us* __restrict__ qb, us* __restrict__ kb, us* __restrict__ vtb) {
  __shared__ __align__(16) char smem_raw[128 * 132 * 4]; // union: sA+sB (32KB) / sC fp32 (67.5KB)
  us* sA = (us*)smem_raw;
  us* sB = sA + 128 * 64;
  float* sC = (float*)smem_raw;

  const int tid = threadIdx.x;
  const int lane = tid & 63;
  const int wave = tid >> 6;
  const int l15 = lane & 15;
  const int lq = lane >> 4;
  const int m0 = blockIdx.x * 128;
  const int n0 = blockIdx.y * 128;
  const int wm = (wave & 1) * 64;
  const int wn = (wave >> 1) * 64;

  f32x4 acc[4][4] = {};

  for (int k0 = 0; k0 < 1024; k0 += 64) {
    for (int i = 0; i < 4; ++i) {
      int c = wave * 4 + i;
      int P = c * 64 + lane;           // 16B slot index
      int row = P >> 3;                // 8 slots per 64-el row
      int cb = (P & 7) ^ (row & 7);    // xor-swizzle
      gll16(A + (size_t)(m0 + row) * 1024 + k0 + cb * 8, sA + c * 512);
      gll16(B + (size_t)(n0 + row) * 1024 + k0 + cb * 8, sB + c * 512);
    }
    __syncthreads();
#pragma unroll
    for (int kk = 0; kk < 64; kk += 32) {
      const int cbr = (kk + lq * 8) >> 3;
      bf16x8 av[4], bv[4];
#pragma unroll
      for (int mt = 0; mt < 4; ++mt) {
        int m = wm + mt * 16 + l15;
        av[mt] = *(const bf16x8*)(sA + (m * 8 + (cbr ^ (m & 7))) * 8);
      }
#pragma unroll
      for (int nt = 0; nt < 4; ++nt) {
        int n = wn + nt * 16 + l15;
        bv[nt] = *(const bf16x8*)(sB + (n * 8 + (cbr ^ (n & 7))) * 8);
      }
#pragma unroll
      for (int mt = 0; mt < 4; ++mt)
#pragma unroll
        for (int nt = 0; nt < 4; ++nt)
          acc[mt][nt] = MFMA16(av[mt], bv[nt], acc[mt][nt]);
    }
    __syncthreads();
  }

  // accumulators -> padded fp32 LDS tile (ld=132)
#pragma unroll
  for (int mt = 0; mt < 4; ++mt)
#pragma unroll
    for (int nt = 0; nt < 4; ++nt)
#pragma unroll
      for (int r = 0; r < 4; ++r) {
        int row = wm + mt * 16 + lq * 4 + r;
        int col = wn + nt * 16 + l15;
        sC[row * 132 + col] = acc[mt][nt][r];
      }
  __syncthreads();

  const int b = m0 >> 12;
  const int t0 = m0 & 4095;
  const int which = blockIdx.y >> 3;
  const int h = blockIdx.y & 7;

  if (which < 2) {
    // RoPE via table: out[d] = x[d]*cos + rot[d]*sin; rot[d] = d<64 ? -x[d+64] : x[d-64]
    us* outp = (which == 0) ? qb : kb;
    for (int r = 0; r < 8; ++r) {
      int tl = (tid >> 4) + r * 16;
      int d0 = (tid & 15) * 8;
      int tg = t0 + tl;
      int dm = d0 & 63;
      float cs[8], sn[8];
      *(float4*)(cs)     = *(const float4*)(ctab + tg * 64 + dm);
      *(float4*)(cs + 4) = *(const float4*)(ctab + tg * 64 + dm + 4);
      *(float4*)(sn)     = *(const float4*)(stab + tg * 64 + dm);
      *(float4*)(sn + 4) = *(const float4*)(stab + tg * 64 + dm + 4);
      union { us u[8]; uint4 v; } tmp;
#pragma unroll
      for (int j = 0; j < 8; ++j) {
        int d = d0 + j;
        float xv = sC[tl * 132 + d];
        float xp = sC[tl * 132 + (d ^ 64)];
        float rot = (d < 64) ? -xp : xp;
        tmp.u[j] = f2bf(xv * cs[j] + rot * sn[j]);
      }
      *(uint4*)(outp + ((size_t)((b * 8 + h) * 4096 + tg)) * 128 + d0) = tmp.v;
    }
  } else {
    // V transpose: vT[b][h][d][t]
    for (int r = 0; r < 8; ++r) {
      int d = (tid >> 4) + r * 16;
      int tl0 = (tid & 15) * 8;
      union { us u[8]; uint4 v; } tmp;
#pragma unroll
      for (int j = 0; j < 8; ++j)
        tmp.u[j] = f2bf(sC[(tl0 + j) * 132 + d]);
      *(uint4*)(vtb + ((size_t)((b * 8 + h) * 128 + d)) * 4096 + t0 + tl0) = tmp.v;
    }
  }
}

// --------------------------------------------------- flash attention --------
// MASK: 0=none (interior tile), 1=window-low (jt==qt-4), 2=causal (jt==qt)
template <int MASK>
__device__ __forceinline__ void softmax_step(f32x4 (&s)[2][8], f32x4 (&o)[2][8],
                                             float (&m_st)[2][4], float (&l_st)[2][4],
                                             int t0, int tj0, int wm, int lq, int l15) {
  const float C2 = 0.08838834764831845f * 1.4426950408889634f; // scale * log2(e)
#pragma unroll
  for (int mt = 0; mt < 2; ++mt) {
#pragma unroll
    for (int r = 0; r < 4; ++r) {
      const int ig = t0 + wm + mt * 16 + lq * 4 + r;
      float mx = -3.0e38f;
#pragma unroll
      for (int nt = 0; nt < 8; ++nt) {
        float v = s[mt][nt][r];
        if (MASK == 1) { int jg = tj0 + nt * 16 + l15; v = (jg + 512 >= ig) ? v : -3.0e38f; }
        if (MASK == 2) { int jg = tj0 + nt * 16 + l15; v = (jg <= ig) ? v : -3.0e38f; }
        s[mt][nt][r] = v;
        mx = fmaxf(mx, v);
      }
#pragma unroll
      for (int off = 1; off < 16; off <<= 1) mx = fmaxf(mx, __shfl_xor(mx, off, 64));
      const float mold = m_st[mt][r];
      const float mnew = fmaxf(mold, mx);
      const float alpha = exp2f((mold - mnew) * C2);
      float rs = 0.0f;
#pragma unroll
      for (int nt = 0; nt < 8; ++nt) {
        float p = exp2f((s[mt][nt][r] - mnew) * C2); // masked: exp2(-huge) = 0
        s[mt][nt][r] = p;
        rs += p;
      }
#pragma unroll
      for (int off = 1; off < 16; off <<= 1) rs += __shfl_xor(rs, off, 64);
      m_st[mt][r] = mnew;
      l_st[mt][r] = l_st[mt][r] * alpha + rs;
#pragma unroll
      for (int dt = 0; dt < 8; ++dt) o[mt][dt][r] *= alpha;
    }
  }
}

// grid (qt=32, h=8, b=2); 128 q-rows/block; window: j in [i-512, i]
__global__ __launch_bounds__(256, 2)
void flash_kernel(const us* __restrict__ qg, const us* __restrict__ kg,
                  const us* __restrict__ vg, us* __restrict__ ao) {
  __shared__ us sKP[128 * 136]; // union: sK swizzled [j][d] (first 128*128) / sP padded ld=136
  __shared__ us sV[128 * 128];  // V^T tile [d][j] swizzled

  const int tid = threadIdx.x;
  const int lane = tid & 63;
  const int wave = tid >> 6;
  const int l15 = lane & 15;
  const int lq = lane >> 4;
  const int qt = blockIdx.x;
  const int h = blockIdx.y;
  const int b = blockIdx.z;
  const int t0 = qt * 128;
  const size_t bh = (size_t)(b * 8 + h);
  const int wm = wave * 32;

  // Q fragments direct to registers (A-layout: A[m=lane&15][k=lq*8+j]), reused all jt
  bf16x8 qf[2][4];
#pragma unroll
  for (int mt = 0; mt < 2; ++mt)
#pragma unroll
    for (int ks = 0; ks < 4; ++ks)
      qf[mt][ks] = *(const bf16x8*)(qg + (bh * 4096 + t0 + wm + mt * 16 + l15) * 128 +
                                    ks * 32 + lq * 8);

  float m_st[2][4], l_st[2][4];
  f32x4 o[2][8] = {};
#pragma unroll
  for (int mt = 0; mt < 2; ++mt)
#pragma unroll
    for (int r = 0; r < 4; ++r) { m_st[mt][r] = -3.0e38f; l_st[mt][r] = 0.0f; }

  int jt0 = qt - 4; if (jt0 < 0) jt0 = 0;

  for (int jt = jt0; jt <= qt; ++jt) {
    const int tj0 = jt * 128;
    for (int i = 0; i < 8; ++i) {
      int c = wave * 8 + i;
      int P = c * 64 + lane;
      int row = P >> 4;
      int cb = (P & 15) ^ (row & 15);
      gll16(kg + (bh * 4096 + tj0 + row) * 128 + cb * 8, sKP + c * 512);
      gll16(vg + (bh * 128 + row) * 4096 + tj0 + cb * 8, sV + c * 512);
    }
    __syncthreads(); // stage visible (vmcnt drained at barrier)

    // S = Q K^T  (each wave: 32 q-rows x 128 keys)
    f32x4 s[2][8] = {};
#pragma unroll
    for (int ks = 0; ks < 4; ++ks) {
      const int cbr = ks * 4 + lq;
#pragma unroll
      for (int nt = 0; nt < 8; ++nt) {
        int n = nt * 16 + l15;
        bf16x8 bk = *(const bf16x8*)(sKP + (n * 16 + (cbr ^ (n & 15))) * 8);
#pragma unroll
        for (int mt = 0; mt < 2; ++mt)
          s[mt][nt] = MFMA16(qf[mt][ks], bk, s[mt][nt]);
      }
    }

    // online softmax, registers only (covers barrier B latency)
    if (jt == qt)          softmax_step<2>(s, o, m_st, l_st, t0, tj0, wm, lq, l15);
    else if (jt == qt - 4) softmax_step<1>(s, o, m_st, l_st, t0, tj0, wm, lq, l15);
    else                   softmax_step<0>(s, o, m_st, l_st, t0, tj0, wm, lq, l15);

    __syncthreads(); // barrier B: all waves done reading sK before sP overwrite

    // P -> LDS (C-layout -> A-layout round trip), own rows only
#pragma unroll
    for (int mt = 0; mt < 2; ++mt)
#pragma unroll
      for (int r = 0; r < 4; ++r) {
        const int rowl = wm + mt * 16 + lq * 4 + r;
#pragma unroll
        for (int nt = 0; nt < 8; ++nt)
          sKP[rowl * 136 + nt * 16 + l15] = f2bf(s[mt][nt][r]);
      }

    // O += P V  (A = sP own rows — wave-internal RAW via waitcnt; B = sV)
#pragma unroll
    for (int ks = 0; ks < 4; ++ks) {
      const int ko = ks * 32 + lq * 8;
      const int cbr = ko >> 3;
      bf16x8 ap[2];
#pragma unroll
      for (int mt = 0; mt < 2; ++mt)
        ap[mt] = *(const bf16x8*)(sKP + (wm + mt * 16 + l15) * 136 + ko);
#pragma unroll
      for (int dt = 0; dt < 8; ++dt) {
        int dd = dt * 16 + l15;
        bf16x8 bv = *(const bf16x8*)(sV + (dd * 16 + (cbr ^ (dd & 15))) * 8);
#pragma unroll
        for (int mt = 0; mt < 2; ++mt)
          o[mt][dt] = MFMA16(ap[mt], bv, o[mt][dt]);
      }
    }
    __syncthreads(); // barrier C: PV reads done before next stage overwrites sKP/sV
  }

  // epilogue: O/l -> ao [b*4096+t][h*128+d] bf16
#pragma unroll
  for (int mt = 0; mt < 2; ++mt)
#pragma unroll
    for (int r = 0; r < 4; ++r) {
      const float inv = 1.0f / l_st[mt][r];
      const int rowl = wm + mt * 16 + lq * 4 + r;
      const size_t base = ((size_t)b * 4096 + t0 + rowl) * 1024 + h * 128;
#pragma unroll
      for (int dt = 0; dt < 8; ++dt)
        ao[base + dt * 16 + l15] = f2bf(o[mt][dt][r] * inv);
    }
}

// ------------------------------------------------ GEMM3: out = ao @ w_o^T ---
__global__ __launch_bounds__(256, 2)
void out_proj_kernel(const us* __restrict__ A, const us* __restrict__ B, float* __restrict__ C) {
  __shared__ us sA[128 * 64];
  __shared__ us sB[128 * 64];
  const int tid = threadIdx.x;
  const int lane = tid & 63;
  const int wave = tid >> 6;
  const int l15 = lane & 15;
  const int lq = lane >> 4;
  const int m0 = blockIdx.x * 128;
  const int n0 = blockIdx.y * 128;
  const int wm = (wave & 1) * 64;
  const int wn = (wave >> 1) * 64;
  f32x4 acc[4][4] = {};
  for (int k0 = 0; k0 < 1024; k0 += 64) {
    for (int i = 0; i < 4; ++i) {
      int c = wave * 4 + i;
      int P = c * 64 + lane;
      int row = P >> 3;
      int cb = (P & 7) ^ (row & 7);
      gll16(A + (size_t)(m0 + row) * 1024 + k0 + cb * 8, sA + c * 512);
      gll16(B + (size_t)(n0 + row) * 1024 + k0 + cb * 8, sB + c * 512);
    }
    __syncthreads();
#pragma unroll
    for (int kk = 0; kk < 64; kk += 32) {
      const int cbr = (kk + lq * 8) >> 3;
      bf16x8 av[4], bv[4];
#pragma unroll
      for (int mt = 0; mt < 4; ++mt) {
        int m = wm + mt * 16 + l15;
        av[mt] = *(const bf16x8*)(sA + (m * 8 + (cbr ^ (m & 7))) * 8);
      }
#pragma unroll
      for (int nt = 0; nt < 4; ++nt) {
        int n = wn + nt * 16 + l15;
        bv[nt] = *(const bf16x8*)(sB + (n * 8 + (cbr ^ (n & 7))) * 8);
      }
#pragma unroll
      for (int mt = 0; mt < 4; ++mt)
#pragma unroll
        for (int nt = 0; nt < 4; ++nt)
          acc[mt][nt] = MFMA16(av[mt], bv[nt], acc[mt][nt]);
    }
    __syncthreads();
  }
#pragma unroll
  for (int mt = 0; mt < 4; ++mt)
#pragma unroll
    for (int nt = 0; nt < 4; ++nt)
#pragma unroll
      for (int r = 0; r < 4; ++r)
        C[(size_t)(m0 + wm + mt * 16 + lq * 4 + r) * 1024 + (n0 + wn + nt * 16 + l15)] =
            acc[mt][nt][r];
}

// ---------------------------------------------------------------- launch ----
extern "C" void kernel_launch(void* const* d_in, const int* in_sizes, int n_in,
                              void* d_out, int out_size, void* d_ws, size_t ws_size,
                              hipStream_t stream) {
  const float* x     = (const float*)d_in[0];  // [2,4096,1024]
  const float* w_qkv = (const float*)d_in[1];  // [3072,1024]
  const float* w_o   = (const float*)d_in[2];  // [1024,1024]
  float* out = (float*)d_out;                  // [2,4096,1024] fp32

  us* xb  = (us*)d_ws;                          // 8192*1024
  us* wqb = xb  + (size_t)8192 * 1024;          // 3072*1024
  us* wob = wqb + (size_t)3072 * 1024;          // 1024*1024
  us* qb  = wob + (size_t)1024 * 1024;          // [2][8][4096][128]
  us* kb  = qb  + (size_t)2 * 8 * 4096 * 128;
  us* vtb = kb  + (size_t)2 * 8 * 4096 * 128;   // [2][8][128][4096]
  us* aob = vtb + (size_t)2 * 8 * 4096 * 128;   // 8192*1024
  float* ctab = (float*)(aob + (size_t)8192 * 1024); // [4096][64]
  float* stab = ctab + (size_t)4096 * 64;

  rope_table_kernel<<<4096, 64, 0, stream>>>(ctab, stab);
  cast_kernel<<<8192, 256, 0, stream>>>(x, xb, 8192 * 1024 / 4);
  cast_kernel<<<3072, 256, 0, stream>>>(w_qkv, wqb, 3072 * 1024 / 4);
  cast_kernel<<<1024, 256, 0, stream>>>(w_o, wob, 1024 * 1024 / 4);
  qkv_rope_kernel<<<dim3(64, 24), 256, 0, stream>>>(xb, wqb, ctab, stab, qb, kb, vtb);
  flash_kernel<<<dim3(32, 8, 2), 256, 0, stream>>>(qb, kb, vtb, aob);
  out_proj_kernel<<<dim3(64, 8), 256, 0, stream>>>(aob, wob, out);
}

// Round 3
// 266.716 us; speedup vs baseline: 1.2065x; 1.2065x over previous
//
#include <hip/hip_runtime.h>
#include <hip/hip_bf16.h>

typedef unsigned short us;
typedef __attribute__((ext_vector_type(8))) __bf16 bf16x8;
typedef __attribute__((ext_vector_type(4))) float f32x4;

#define MFMA16(a, b, c) __builtin_amdgcn_mfma_f32_16x16x32_bf16(a, b, c, 0, 0, 0)

static __device__ __forceinline__ us f2bf(float f) {
  __hip_bfloat16 h = __float2bfloat16(f);
  return __builtin_bit_cast(us, h);
}

// async global->LDS, 16B per lane; LDS dest is wave-uniform base + lane*16
static __device__ __forceinline__ void gll16(const us* g, us* l) {
  __builtin_amdgcn_global_load_lds((const __attribute__((address_space(1))) void*)g,
                                   (__attribute__((address_space(3))) void*)l,
                                   16, 0, 0);
}

// ---------------------------------------------------------------- casts ----
__global__ void cast_kernel(const float* __restrict__ in, us* __restrict__ out, int n4) {
  int i = blockIdx.x * blockDim.x + threadIdx.x;
  if (i >= n4) return;
  float4 v = ((const float4*)in)[i];
  ushort4 o;
  o.x = f2bf(v.x); o.y = f2bf(v.y); o.z = f2bf(v.z); o.w = f2bf(v.w);
  ((ushort4*)out)[i] = o;
}

// -------------------------------------------------------------- rope tab ----
__global__ void rope_table_kernel(float* __restrict__ ct, float* __restrict__ st) {
  int t = blockIdx.x, d = threadIdx.x;
  float ang = (float)t * exp2f((float)d * -0.20762050593046014f);
  float s, c;
  sincosf(ang, &s, &c);
  ct[t * 64 + d] = c;
  st[t * 64 + d] = s;
}

// ------------------------------------------- GEMM1: qkv + RoPE + scatter ----
// A = xb [8192][1024], B = wqb [3072][1024] (out[m][n]=sum_k A[m,k]B[n,k])
// epilogue: which=by/8 (0=q,1=k,2=v), h=by%8; q/k roped -> [b][h][t][128]; v -> vT [b][h][128][4096]
__global__ __launch_bounds__(256, 2)
void qkv_rope_kernel(const us* __restrict__ A, const us* __restrict__ B,
                     const float* __restrict__ ctab, const float* __restrict__ stab,
                     us* __restrict__ qb, us* __restrict__ kb, us* __restrict__ vtb) {
  __shared__ __align__(16) char smem_raw[128 * 132 * 4]; // union: sA+sB (32KB) / sC fp32 (67.5KB)
  us* sA = (us*)smem_raw;
  us* sB = sA + 128 * 64;
  float* sC = (float*)smem_raw;

  const int tid = threadIdx.x;
  const int lane = tid & 63;
  const int wave = tid >> 6;
  const int l15 = lane & 15;
  const int lq = lane >> 4;
  const int m0 = blockIdx.x * 128;
  const int n0 = blockIdx.y * 128;
  const int wm = (wave & 1) * 64;
  const int wn = (wave >> 1) * 64;

  f32x4 acc[4][4] = {};

  for (int k0 = 0; k0 < 1024; k0 += 64) {
    for (int i = 0; i < 4; ++i) {
      int c = wave * 4 + i;
      int P = c * 64 + lane;           // 16B slot index
      int row = P >> 3;                // 8 slots per 64-el row
      int cb = (P & 7) ^ (row & 7);    // xor-swizzle
      gll16(A + (size_t)(m0 + row) * 1024 + k0 + cb * 8, sA + c * 512);
      gll16(B + (size_t)(n0 + row) * 1024 + k0 + cb * 8, sB + c * 512);
    }
    __syncthreads();
#pragma unroll
    for (int kk = 0; kk < 64; kk += 32) {
      const int cbr = (kk + lq * 8) >> 3;
      bf16x8 av[4], bv[4];
#pragma unroll
      for (int mt = 0; mt < 4; ++mt) {
        int m = wm + mt * 16 + l15;
        av[mt] = *(const bf16x8*)(sA + (m * 8 + (cbr ^ (m & 7))) * 8);
      }
#pragma unroll
      for (int nt = 0; nt < 4; ++nt) {
        int n = wn + nt * 16 + l15;
        bv[nt] = *(const bf16x8*)(sB + (n * 8 + (cbr ^ (n & 7))) * 8);
      }
#pragma unroll
      for (int mt = 0; mt < 4; ++mt)
#pragma unroll
        for (int nt = 0; nt < 4; ++nt)
          acc[mt][nt] = MFMA16(av[mt], bv[nt], acc[mt][nt]);
    }
    __syncthreads();
  }

  // accumulators -> padded fp32 LDS tile (ld=132)
#pragma unroll
  for (int mt = 0; mt < 4; ++mt)
#pragma unroll
    for (int nt = 0; nt < 4; ++nt)
#pragma unroll
      for (int r = 0; r < 4; ++r) {
        int row = wm + mt * 16 + lq * 4 + r;
        int col = wn + nt * 16 + l15;
        sC[row * 132 + col] = acc[mt][nt][r];
      }
  __syncthreads();

  const int b = m0 >> 12;
  const int t0 = m0 & 4095;
  const int which = blockIdx.y >> 3;
  const int h = blockIdx.y & 7;

  if (which < 2) {
    // RoPE via table: out[d] = x[d]*cos + rot[d]*sin; rot[d] = d<64 ? -x[d+64] : x[d-64]
    us* outp = (which == 0) ? qb : kb;
    for (int r = 0; r < 8; ++r) {
      int tl = (tid >> 4) + r * 16;
      int d0 = (tid & 15) * 8;
      int tg = t0 + tl;
      int dm = d0 & 63;
      float cs[8], sn[8];
      *(float4*)(cs)     = *(const float4*)(ctab + tg * 64 + dm);
      *(float4*)(cs + 4) = *(const float4*)(ctab + tg * 64 + dm + 4);
      *(float4*)(sn)     = *(const float4*)(stab + tg * 64 + dm);
      *(float4*)(sn + 4) = *(const float4*)(stab + tg * 64 + dm + 4);
      union { us u[8]; uint4 v; } tmp;
#pragma unroll
      for (int j = 0; j < 8; ++j) {
        int d = d0 + j;
        float xv = sC[tl * 132 + d];
        float xp = sC[tl * 132 + (d ^ 64)];
        float rot = (d < 64) ? -xp : xp;
        tmp.u[j] = f2bf(xv * cs[j] + rot * sn[j]);
      }
      *(uint4*)(outp + ((size_t)((b * 8 + h) * 4096 + tg)) * 128 + d0) = tmp.v;
    }
  } else {
    // V transpose: vT[b][h][d][t]
    for (int r = 0; r < 8; ++r) {
      int d = (tid >> 4) + r * 16;
      int tl0 = (tid & 15) * 8;
      union { us u[8]; uint4 v; } tmp;
#pragma unroll
      for (int j = 0; j < 8; ++j)
        tmp.u[j] = f2bf(sC[(tl0 + j) * 132 + d]);
      *(uint4*)(vtb + ((size_t)((b * 8 + h) * 128 + d)) * 4096 + t0 + tl0) = tmp.v;
    }
  }
}

// --------------------------------------------------- flash attention --------
// MASK: 0=none (interior tile), 1=window-low (jt==qt-4), 2=causal (jt==qt)
template <int MASK>
__device__ __forceinline__ void softmax_step(f32x4 (&s)[2][8], f32x4 (&o)[2][8],
                                             float (&m_st)[2][4], float (&l_st)[2][4],
                                             int t0, int tj0, int wm, int lq, int l15) {
  const float C2 = 0.08838834764831845f * 1.4426950408889634f; // scale * log2(e)
#pragma unroll
  for (int mt = 0; mt < 2; ++mt) {
#pragma unroll
    for (int r = 0; r < 4; ++r) {
      const int ig = t0 + wm + mt * 16 + lq * 4 + r;
      float mx = -3.0e38f;
#pragma unroll
      for (int nt = 0; nt < 8; ++nt) {
        float v = s[mt][nt][r];
        if (MASK == 1) { int jg = tj0 + nt * 16 + l15; v = (jg + 512 >= ig) ? v : -3.0e38f; }
        if (MASK == 2) { int jg = tj0 + nt * 16 + l15; v = (jg <= ig) ? v : -3.0e38f; }
        s[mt][nt][r] = v;
        mx = fmaxf(mx, v);
      }
#pragma unroll
      for (int off = 1; off < 16; off <<= 1) mx = fmaxf(mx, __shfl_xor(mx, off, 64));
      const float mold = m_st[mt][r];
      const float mnew = fmaxf(mold, mx);
      const float alpha = exp2f((mold - mnew) * C2);
      float rs = 0.0f;
#pragma unroll
      for (int nt = 0; nt < 8; ++nt) {
        float p = exp2f((s[mt][nt][r] - mnew) * C2); // masked: exp2(-huge) = 0
        s[mt][nt][r] = p;
        rs += p;
      }
#pragma unroll
      for (int off = 1; off < 16; off <<= 1) rs += __shfl_xor(rs, off, 64);
      m_st[mt][r] = mnew;
      l_st[mt][r] = l_st[mt][r] * alpha + rs;
#pragma unroll
      for (int dt = 0; dt < 8; ++dt) o[mt][dt][r] *= alpha;
    }
  }
}

// grid (qt=32, h=8, b=2); 128 q-rows/block; window: j in [i-512, i]
// NOTE: launch_bounds (256,1), NOT (256,2): declaring 2 waves/EU capped the
// allocator at 128 VGPRs and spilled ~400 MB/launch to scratch (R2 post-mortem).
// Actual demand ~205 regs <= 256 -> HW gives 2 blocks/CU from usage alone.
__global__ __launch_bounds__(256, 1)
void flash_kernel(const us* __restrict__ qg, const us* __restrict__ kg,
                  const us* __restrict__ vg, us* __restrict__ ao) {
  __shared__ us sKP[128 * 136]; // union: sK swizzled [j][d] (first 128*128) / sP padded ld=136
  __shared__ us sV[128 * 128];  // V^T tile [d][j] swizzled

  const int tid = threadIdx.x;
  const int lane = tid & 63;
  const int wave = tid >> 6;
  const int l15 = lane & 15;
  const int lq = lane >> 4;
  const int qt = blockIdx.x;
  const int h = blockIdx.y;
  const int b = blockIdx.z;
  const int t0 = qt * 128;
  const size_t bh = (size_t)(b * 8 + h);
  const int wm = wave * 32;

  // Q fragments direct to registers (A-layout: A[m=lane&15][k=lq*8+j]), reused all jt
  bf16x8 qf[2][4];
#pragma unroll
  for (int mt = 0; mt < 2; ++mt)
#pragma unroll
    for (int ks = 0; ks < 4; ++ks)
      qf[mt][ks] = *(const bf16x8*)(qg + (bh * 4096 + t0 + wm + mt * 16 + l15) * 128 +
                                    ks * 32 + lq * 8);

  float m_st[2][4], l_st[2][4];
  f32x4 o[2][8] = {};
#pragma unroll
  for (int mt = 0; mt < 2; ++mt)
#pragma unroll
    for (int r = 0; r < 4; ++r) { m_st[mt][r] = -3.0e38f; l_st[mt][r] = 0.0f; }

  int jt0 = qt - 4; if (jt0 < 0) jt0 = 0;

  for (int jt = jt0; jt <= qt; ++jt) {
    const int tj0 = jt * 128;
    for (int i = 0; i < 8; ++i) {
      int c = wave * 8 + i;
      int P = c * 64 + lane;
      int row = P >> 4;
      int cb = (P & 15) ^ (row & 15);
      gll16(kg + (bh * 4096 + tj0 + row) * 128 + cb * 8, sKP + c * 512);
      gll16(vg + (bh * 128 + row) * 4096 + tj0 + cb * 8, sV + c * 512);
    }
    __syncthreads(); // stage visible (vmcnt drained at barrier)

    // S = Q K^T  (each wave: 32 q-rows x 128 keys)
    f32x4 s[2][8] = {};
#pragma unroll
    for (int ks = 0; ks < 4; ++ks) {
      const int cbr = ks * 4 + lq;
#pragma unroll
      for (int nt = 0; nt < 8; ++nt) {
        int n = nt * 16 + l15;
        bf16x8 bk = *(const bf16x8*)(sKP + (n * 16 + (cbr ^ (n & 15))) * 8);
#pragma unroll
        for (int mt = 0; mt < 2; ++mt)
          s[mt][nt] = MFMA16(qf[mt][ks], bk, s[mt][nt]);
      }
    }

    // online softmax, registers only (covers barrier B latency)
    if (jt == qt)          softmax_step<2>(s, o, m_st, l_st, t0, tj0, wm, lq, l15);
    else if (jt == qt - 4) softmax_step<1>(s, o, m_st, l_st, t0, tj0, wm, lq, l15);
    else                   softmax_step<0>(s, o, m_st, l_st, t0, tj0, wm, lq, l15);

    __syncthreads(); // barrier B: all waves done reading sK before sP overwrite

    // P -> LDS (C-layout -> A-layout round trip), own rows only
#pragma unroll
    for (int mt = 0; mt < 2; ++mt)
#pragma unroll
      for (int r = 0; r < 4; ++r) {
        const int rowl = wm + mt * 16 + lq * 4 + r;
#pragma unroll
        for (int nt = 0; nt < 8; ++nt)
          sKP[rowl * 136 + nt * 16 + l15] = f2bf(s[mt][nt][r]);
      }

    // O += P V  (A = sP own rows — wave-internal RAW via waitcnt; B = sV)
#pragma unroll
    for (int ks = 0; ks < 4; ++ks) {
      const int ko = ks * 32 + lq * 8;
      const int cbr = ko >> 3;
      bf16x8 ap[2];
#pragma unroll
      for (int mt = 0; mt < 2; ++mt)
        ap[mt] = *(const bf16x8*)(sKP + (wm + mt * 16 + l15) * 136 + ko);
#pragma unroll
      for (int dt = 0; dt < 8; ++dt) {
        int dd = dt * 16 + l15;
        bf16x8 bv = *(const bf16x8*)(sV + (dd * 16 + (cbr ^ (dd & 15))) * 8);
#pragma unroll
        for (int mt = 0; mt < 2; ++mt)
          o[mt][dt] = MFMA16(ap[mt], bv, o[mt][dt]);
      }
    }
    __syncthreads(); // barrier C: PV reads done before next stage overwrites sKP/sV
  }

  // epilogue: O/l -> ao [b*4096+t][h*128+d] bf16
#pragma unroll
  for (int mt = 0; mt < 2; ++mt)
#pragma unroll
    for (int r = 0; r < 4; ++r) {
      const float inv = 1.0f / l_st[mt][r];
      const int rowl = wm + mt * 16 + lq * 4 + r;
      const size_t base = ((size_t)b * 4096 + t0 + rowl) * 1024 + h * 128;
#pragma unroll
      for (int dt = 0; dt < 8; ++dt)
        ao[base + dt * 16 + l15] = f2bf(o[mt][dt][r] * inv);
    }
}

// ------------------------------------------------ GEMM3: out = ao @ w_o^T ---
__global__ __launch_bounds__(256, 2)
void out_proj_kernel(const us* __restrict__ A, const us* __restrict__ B, float* __restrict__ C) {
  __shared__ us sA[128 * 64];
  __shared__ us sB[128 * 64];
  const int tid = threadIdx.x;
  const int lane = tid & 63;
  const int wave = tid >> 6;
  const int l15 = lane & 15;
  const int lq = lane >> 4;
  const int m0 = blockIdx.x * 128;
  const int n0 = blockIdx.y * 128;
  const int wm = (wave & 1) * 64;
  const int wn = (wave >> 1) * 64;
  f32x4 acc[4][4] = {};
  for (int k0 = 0; k0 < 1024; k0 += 64) {
    for (int i = 0; i < 4; ++i) {
      int c = wave * 4 + i;
      int P = c * 64 + lane;
      int row = P >> 3;
      int cb = (P & 7) ^ (row & 7);
      gll16(A + (size_t)(m0 + row) * 1024 + k0 + cb * 8, sA + c * 512);
      gll16(B + (size_t)(n0 + row) * 1024 + k0 + cb * 8, sB + c * 512);
    }
    __syncthreads();
#pragma unroll
    for (int kk = 0; kk < 64; kk += 32) {
      const int cbr = (kk + lq * 8) >> 3;
      bf16x8 av[4], bv[4];
#pragma unroll
      for (int mt = 0; mt < 4; ++mt) {
        int m = wm + mt * 16 + l15;
        av[mt] = *(const bf16x8*)(sA + (m * 8 + (cbr ^ (m & 7))) * 8);
      }
#pragma unroll
      for (int nt = 0; nt < 4; ++nt) {
        int n = wn + nt * 16 + l15;
        bv[nt] = *(const bf16x8*)(sB + (n * 8 + (cbr ^ (n & 7))) * 8);
      }
#pragma unroll
      for (int mt = 0; mt < 4; ++mt)
#pragma unroll
        for (int nt = 0; nt < 4; ++nt)
          acc[mt][nt] = MFMA16(av[mt], bv[nt], acc[mt][nt]);
    }
    __syncthreads();
  }
#pragma unroll
  for (int mt = 0; mt < 4; ++mt)
#pragma unroll
    for (int nt = 0; nt < 4; ++nt)
#pragma unroll
      for (int r = 0; r < 4; ++r)
        C[(size_t)(m0 + wm + mt * 16 + lq * 4 + r) * 1024 + (n0 + wn + nt * 16 + l15)] =
            acc[mt][nt][r];
}

// ---------------------------------------------------------------- launch ----
extern "C" void kernel_launch(void* const* d_in, const int* in_sizes, int n_in,
                              void* d_out, int out_size, void* d_ws, size_t ws_size,
                              hipStream_t stream) {
  const float* x     = (const float*)d_in[0];  // [2,4096,1024]
  const float* w_qkv = (const float*)d_in[1];  // [3072,1024]
  const float* w_o   = (const float*)d_in[2];  // [1024,1024]
  float* out = (float*)d_out;                  // [2,4096,1024] fp32

  us* xb  = (us*)d_ws;                          // 8192*1024
  us* wqb = xb  + (size_t)8192 * 1024;          // 3072*1024
  us* wob = wqb + (size_t)3072 * 1024;          // 1024*1024
  us* qb  = wob + (size_t)1024 * 1024;          // [2][8][4096][128]
  us* kb  = qb  + (size_t)2 * 8 * 4096 * 128;
  us* vtb = kb  + (size_t)2 * 8 * 4096 * 128;   // [2][8][128][4096]
  us* aob = vtb + (size_t)2 * 8 * 4096 * 128;   // 8192*1024
  float* ctab = (float*)(aob + (size_t)8192 * 1024); // [4096][64]
  float* stab = ctab + (size_t)4096 * 64;

  rope_table_kernel<<<4096, 64, 0, stream>>>(ctab, stab);
  cast_kernel<<<8192, 256, 0, stream>>>(x, xb, 8192 * 1024 / 4);
  cast_kernel<<<3072, 256, 0, stream>>>(w_qkv, wqb, 3072 * 1024 / 4);
  cast_kernel<<<1024, 256, 0, stream>>>(w_o, wob, 1024 * 1024 / 4);
  qkv_rope_kernel<<<dim3(64, 24), 256, 0, stream>>>(xb, wqb, ctab, stab, qb, kb, vtb);
  flash_kernel<<<dim3(32, 8, 2), 256, 0, stream>>>(qb, kb, vtb, aob);
  out_proj_kernel<<<dim3(64, 8), 256, 0, stream>>>(aob, wob, out);
}

// Round 4
// 248.138 us; speedup vs baseline: 1.2969x; 1.0749x over previous
//
#include <hip/hip_runtime.h>
#include <hip/hip_bf16.h>

typedef unsigned short us;
typedef __attribute__((ext_vector_type(8))) __bf16 bf16x8;
typedef __attribute__((ext_vector_type(4))) float f32x4;

#define MFMA16(a, b, c) __builtin_amdgcn_mfma_f32_16x16x32_bf16(a, b, c, 0, 0, 0)

static __device__ __forceinline__ us f2bf(float f) {
  __hip_bfloat16 h = __float2bfloat16(f);
  return __builtin_bit_cast(us, h);
}

// async global->LDS, 16B per lane; LDS dest is wave-uniform base + lane*16
static __device__ __forceinline__ void gll16(const us* g, us* l) {
  __builtin_amdgcn_global_load_lds((const __attribute__((address_space(1))) void*)g,
                                   (__attribute__((address_space(3))) void*)l,
                                   16, 0, 0);
}

// ---------------------------------------------------------------- casts ----
__global__ void cast_kernel(const float* __restrict__ in, us* __restrict__ out, int n4) {
  int i = blockIdx.x * blockDim.x + threadIdx.x;
  if (i >= n4) return;
  float4 v = ((const float4*)in)[i];
  ushort4 o;
  o.x = f2bf(v.x); o.y = f2bf(v.y); o.z = f2bf(v.z); o.w = f2bf(v.w);
  ((ushort4*)out)[i] = o;
}

// -------------------------------------------------------------- rope tab ----
__global__ void rope_table_kernel(float* __restrict__ ct, float* __restrict__ st) {
  int t = blockIdx.x, d = threadIdx.x;
  float ang = (float)t * exp2f((float)d * -0.20762050593046014f);
  float s, c;
  sincosf(ang, &s, &c);
  ct[t * 64 + d] = c;
  st[t * 64 + d] = s;
}

// ------------------------------------------- GEMM1: qkv + RoPE + scatter ----
// A = xb [8192][1024], B = wqb [3072][1024] (out[m][n]=sum_k A[m,k]B[n,k])
// epilogue: which=by/8 (0=q,1=k,2=v), h=by%8; q/k roped -> [b][h][t][128]; v -> vT [b][h][128][4096]
__global__ __launch_bounds__(256, 2)
void qkv_rope_kernel(const us* __restrict__ A, const us* __restrict__ B,
                     const float* __restrict__ ctab, const float* __restrict__ stab,
                     us* __restrict__ qb, us* __restrict__ kb, us* __restrict__ vtb) {
  __shared__ __align__(16) char smem_raw[128 * 132 * 4]; // union: sA+sB (32KB) / sC fp32 (67.5KB)
  us* sA = (us*)smem_raw;
  us* sB = sA + 128 * 64;
  float* sC = (float*)smem_raw;

  const int tid = threadIdx.x;
  const int lane = tid & 63;
  const int wave = tid >> 6;
  const int l15 = lane & 15;
  const int lq = lane >> 4;
  const int m0 = blockIdx.x * 128;
  const int n0 = blockIdx.y * 128;
  const int wm = (wave & 1) * 64;
  const int wn = (wave >> 1) * 64;

  f32x4 acc[4][4] = {};

  for (int k0 = 0; k0 < 1024; k0 += 64) {
    for (int i = 0; i < 4; ++i) {
      int c = wave * 4 + i;
      int P = c * 64 + lane;           // 16B slot index
      int row = P >> 3;                // 8 slots per 64-el row
      int cb = (P & 7) ^ (row & 7);    // xor-swizzle
      gll16(A + (size_t)(m0 + row) * 1024 + k0 + cb * 8, sA + c * 512);
      gll16(B + (size_t)(n0 + row) * 1024 + k0 + cb * 8, sB + c * 512);
    }
    __syncthreads();
#pragma unroll
    for (int kk = 0; kk < 64; kk += 32) {
      const int cbr = (kk + lq * 8) >> 3;
      bf16x8 av[4], bv[4];
#pragma unroll
      for (int mt = 0; mt < 4; ++mt) {
        int m = wm + mt * 16 + l15;
        av[mt] = *(const bf16x8*)(sA + (m * 8 + (cbr ^ (m & 7))) * 8);
      }
#pragma unroll
      for (int nt = 0; nt < 4; ++nt) {
        int n = wn + nt * 16 + l15;
        bv[nt] = *(const bf16x8*)(sB + (n * 8 + (cbr ^ (n & 7))) * 8);
      }
#pragma unroll
      for (int mt = 0; mt < 4; ++mt)
#pragma unroll
        for (int nt = 0; nt < 4; ++nt)
          acc[mt][nt] = MFMA16(av[mt], bv[nt], acc[mt][nt]);
    }
    __syncthreads();
  }

  // accumulators -> padded fp32 LDS tile (ld=132)
#pragma unroll
  for (int mt = 0; mt < 4; ++mt)
#pragma unroll
    for (int nt = 0; nt < 4; ++nt)
#pragma unroll
      for (int r = 0; r < 4; ++r) {
        int row = wm + mt * 16 + lq * 4 + r;
        int col = wn + nt * 16 + l15;
        sC[row * 132 + col] = acc[mt][nt][r];
      }
  __syncthreads();

  const int b = m0 >> 12;
  const int t0 = m0 & 4095;
  const int which = blockIdx.y >> 3;
  const int h = blockIdx.y & 7;

  if (which < 2) {
    // RoPE via table: out[d] = x[d]*cos + rot[d]*sin; rot[d] = d<64 ? -x[d+64] : x[d-64]
    us* outp = (which == 0) ? qb : kb;
    for (int r = 0; r < 8; ++r) {
      int tl = (tid >> 4) + r * 16;
      int d0 = (tid & 15) * 8;
      int tg = t0 + tl;
      int dm = d0 & 63;
      float cs[8], sn[8];
      *(float4*)(cs)     = *(const float4*)(ctab + tg * 64 + dm);
      *(float4*)(cs + 4) = *(const float4*)(ctab + tg * 64 + dm + 4);
      *(float4*)(sn)     = *(const float4*)(stab + tg * 64 + dm);
      *(float4*)(sn + 4) = *(const float4*)(stab + tg * 64 + dm + 4);
      union { us u[8]; uint4 v; } tmp;
#pragma unroll
      for (int j = 0; j < 8; ++j) {
        int d = d0 + j;
        float xv = sC[tl * 132 + d];
        float xp = sC[tl * 132 + (d ^ 64)];
        float rot = (d < 64) ? -xp : xp;
        tmp.u[j] = f2bf(xv * cs[j] + rot * sn[j]);
      }
      *(uint4*)(outp + ((size_t)((b * 8 + h) * 4096 + tg)) * 128 + d0) = tmp.v;
    }
  } else {
    // V transpose: vT[b][h][d][t]
    for (int r = 0; r < 8; ++r) {
      int d = (tid >> 4) + r * 16;
      int tl0 = (tid & 15) * 8;
      union { us u[8]; uint4 v; } tmp;
#pragma unroll
      for (int j = 0; j < 8; ++j)
        tmp.u[j] = f2bf(sC[(tl0 + j) * 132 + d]);
      *(uint4*)(vtb + ((size_t)((b * 8 + h) * 128 + d)) * 4096 + t0 + tl0) = tmp.v;
    }
  }
}

// --------------------------------------------------- flash attention --------
// MASK: 0=none (interior tile), 1=window-low (first tile, t0>=512), 2=causal (last)
// 16 q-rows per wave; P-write interleaved into softmax (own rows -> wave-internal RAW)
template <int MASK>
__device__ __forceinline__ void softmax_step(f32x4 (&s)[8], f32x4 (&o)[8],
                                             float (&m_st)[4], float (&l_st)[4],
                                             us* __restrict__ sP,
                                             int t0, int tj0, int wm16, int lq, int l15) {
  const float C2 = 0.08838834764831845f * 1.4426950408889634f; // scale * log2(e)
#pragma unroll
  for (int r = 0; r < 4; ++r) {
    const int rowl = wm16 + lq * 4 + r;
    const int ig = t0 + rowl;
    float mx = -3.0e38f;
#pragma unroll
    for (int nt = 0; nt < 8; ++nt) {
      float v = s[nt][r];
      if (MASK == 1) { int jg = tj0 + nt * 16 + l15; v = (jg + 512 >= ig) ? v : -3.0e38f; }
      if (MASK == 2) { int jg = tj0 + nt * 16 + l15; v = (jg <= ig) ? v : -3.0e38f; }
      s[nt][r] = v;
      mx = fmaxf(mx, v);
    }
#pragma unroll
    for (int off = 1; off < 16; off <<= 1) mx = fmaxf(mx, __shfl_xor(mx, off, 64));
    const float mold = m_st[r];
    const float mnew = fmaxf(mold, mx);
    const float alpha = exp2f((mold - mnew) * C2);
    float rs = 0.0f;
#pragma unroll
    for (int nt = 0; nt < 8; ++nt) {
      float p = exp2f((s[nt][r] - mnew) * C2); // masked: exp2(-huge) = 0
      sP[rowl * 136 + nt * 16 + l15] = f2bf(p); // interleaved write, own row
      rs += p;
    }
#pragma unroll
    for (int off = 1; off < 16; off <<= 1) rs += __shfl_xor(rs, off, 64);
    m_st[r] = mnew;
    l_st[r] = l_st[r] * alpha + rs;
#pragma unroll
    for (int dt = 0; dt < 8; ++dt) o[dt][r] *= alpha;
  }
}

// grid (qx=64, h=8, b=2); 64 q-rows/block (16/wave); window: j in [i-512, i]
// (256,2): total-reg cap 256/wave == exactly the 2-blocks/CU requirement; actual
// demand ~120 (80 arch + 64 acc) so no spill (R2 lesson: never cap below demand).
__global__ __launch_bounds__(256, 2)
void flash_kernel(const us* __restrict__ qg, const us* __restrict__ kg,
                  const us* __restrict__ vg, us* __restrict__ ao) {
  __shared__ us sKP[128 * 128]; // union: sK swizzled [j][d] / sP padded 64x136 (17KB)
  __shared__ us sV[128 * 128];  // V^T tile [d][j] swizzled

  const int tid = threadIdx.x;
  const int lane = tid & 63;
  const int wave = tid >> 6;
  const int l15 = lane & 15;
  const int lq = lane >> 4;
  const int qx = blockIdx.x;
  const int h = blockIdx.y;
  const int b = blockIdx.z;
  const int t0 = qx * 64;
  const size_t bh = (size_t)(b * 8 + h);
  const int wm16 = wave * 16;

  // Q fragments direct to registers (A-layout: A[m=lane&15][k=lq*8+j])
  bf16x8 qf[4];
#pragma unroll
  for (int ks = 0; ks < 4; ++ks)
    qf[ks] = *(const bf16x8*)(qg + (bh * 4096 + t0 + wm16 + l15) * 128 + ks * 32 + lq * 8);

  float m_st[4], l_st[4];
  f32x4 o[8] = {};
#pragma unroll
  for (int r = 0; r < 4; ++r) { m_st[r] = -3.0e38f; l_st[r] = 0.0f; }

  const int lo = t0 - 512;
  const int jtmin = (lo <= 0) ? 0 : (lo >> 7);
  const int jtmax = (t0 + 63) >> 7;
  const bool wmask = (t0 >= 512);

  for (int jt = jtmin; jt <= jtmax; ++jt) {
    const int tj0 = jt * 128;
    for (int i = 0; i < 8; ++i) {
      int c = wave * 8 + i;
      int P = c * 64 + lane;
      int row = P >> 4;
      int cb = (P & 15) ^ (row & 15);
      gll16(kg + (bh * 4096 + tj0 + row) * 128 + cb * 8, sKP + c * 512);
      gll16(vg + (bh * 128 + row) * 4096 + tj0 + cb * 8, sV + c * 512);
    }
    __syncthreads(); // A: stage visible

    // S = Q K^T  (each wave: 16 q-rows x 128 keys)
    f32x4 s[8] = {};
#pragma unroll
    for (int ks = 0; ks < 4; ++ks) {
      const int cbr = ks * 4 + lq;
#pragma unroll
      for (int nt = 0; nt < 8; ++nt) {
        int n = nt * 16 + l15;
        bf16x8 bk = *(const bf16x8*)(sKP + (n * 16 + (cbr ^ (n & 15))) * 8);
        s[nt] = MFMA16(qf[ks], bk, s[nt]);
      }
    }
    __syncthreads(); // B: all waves done reading sK; sP overwrite now legal

    // softmax + interleaved P-write (own rows only)
    if (jt == jtmax)               softmax_step<2>(s, o, m_st, l_st, sKP, t0, tj0, wm16, lq, l15);
    else if (wmask && jt == jtmin) softmax_step<1>(s, o, m_st, l_st, sKP, t0, tj0, wm16, lq, l15);
    else                           softmax_step<0>(s, o, m_st, l_st, sKP, t0, tj0, wm16, lq, l15);

    // O += P V  (A = sP own rows — wave-internal RAW via lgkmcnt; B = sV)
#pragma unroll
    for (int ks = 0; ks < 4; ++ks) {
      const int ko = ks * 32 + lq * 8;
      const int cbr = ko >> 3;
      bf16x8 ap = *(const bf16x8*)(sKP + (wm16 + l15) * 136 + ko);
#pragma unroll
      for (int dt = 0; dt < 8; ++dt) {
        int dd = dt * 16 + l15;
        bf16x8 bv = *(const bf16x8*)(sV + (dd * 16 + (cbr ^ (dd & 15))) * 8);
        o[dt] = MFMA16(ap, bv, o[dt]);
      }
    }
    __syncthreads(); // C: PV reads done before next stage overwrites sKP/sV
  }

  // epilogue: O/l -> ao [b*4096+t][h*128+d] bf16
#pragma unroll
  for (int r = 0; r < 4; ++r) {
    const float inv = 1.0f / l_st[r];
    const int rowl = wm16 + lq * 4 + r;
    const size_t base = ((size_t)b * 4096 + t0 + rowl) * 1024 + h * 128;
#pragma unroll
    for (int dt = 0; dt < 8; ++dt)
      ao[base + dt * 16 + l15] = f2bf(o[dt][r] * inv);
  }
}

// ------------------------------------------------ GEMM3: out = ao @ w_o^T ---
__global__ __launch_bounds__(256, 2)
void out_proj_kernel(const us* __restrict__ A, const us* __restrict__ B, float* __restrict__ C) {
  __shared__ us sA[128 * 64];
  __shared__ us sB[128 * 64];
  const int tid = threadIdx.x;
  const int lane = tid & 63;
  const int wave = tid >> 6;
  const int l15 = lane & 15;
  const int lq = lane >> 4;
  const int m0 = blockIdx.x * 128;
  const int n0 = blockIdx.y * 128;
  const int wm = (wave & 1) * 64;
  const int wn = (wave >> 1) * 64;
  f32x4 acc[4][4] = {};
  for (int k0 = 0; k0 < 1024; k0 += 64) {
    for (int i = 0; i < 4; ++i) {
      int c = wave * 4 + i;
      int P = c * 64 + lane;
      int row = P >> 3;
      int cb = (P & 7) ^ (row & 7);
      gll16(A + (size_t)(m0 + row) * 1024 + k0 + cb * 8, sA + c * 512);
      gll16(B + (size_t)(n0 + row) * 1024 + k0 + cb * 8, sB + c * 512);
    }
    __syncthreads();
#pragma unroll
    for (int kk = 0; kk < 64; kk += 32) {
      const int cbr = (kk + lq * 8) >> 3;
      bf16x8 av[4], bv[4];
#pragma unroll
      for (int mt = 0; mt < 4; ++mt) {
        int m = wm + mt * 16 + l15;
        av[mt] = *(const bf16x8*)(sA + (m * 8 + (cbr ^ (m & 7))) * 8);
      }
#pragma unroll
      for (int nt = 0; nt < 4; ++nt) {
        int n = wn + nt * 16 + l15;
        bv[nt] = *(const bf16x8*)(sB + (n * 8 + (cbr ^ (n & 7))) * 8);
      }
#pragma unroll
      for (int mt = 0; mt < 4; ++mt)
#pragma unroll
        for (int nt = 0; nt < 4; ++nt)
          acc[mt][nt] = MFMA16(av[mt], bv[nt], acc[mt][nt]);
    }
    __syncthreads();
  }
#pragma unroll
  for (int mt = 0; mt < 4; ++mt)
#pragma unroll
    for (int nt = 0; nt < 4; ++nt)
#pragma unroll
      for (int r = 0; r < 4; ++r)
        C[(size_t)(m0 + wm + mt * 16 + lq * 4 + r) * 1024 + (n0 + wn + nt * 16 + l15)] =
            acc[mt][nt][r];
}

// ---------------------------------------------------------------- launch ----
extern "C" void kernel_launch(void* const* d_in, const int* in_sizes, int n_in,
                              void* d_out, int out_size, void* d_ws, size_t ws_size,
                              hipStream_t stream) {
  const float* x     = (const float*)d_in[0];  // [2,4096,1024]
  const float* w_qkv = (const float*)d_in[1];  // [3072,1024]
  const float* w_o   = (const float*)d_in[2];  // [1024,1024]
  float* out = (float*)d_out;                  // [2,4096,1024] fp32

  us* xb  = (us*)d_ws;                          // 8192*1024
  us* wqb = xb  + (size_t)8192 * 1024;          // 3072*1024
  us* wob = wqb + (size_t)3072 * 1024;          // 1024*1024
  us* qb  = wob + (size_t)1024 * 1024;          // [2][8][4096][128]
  us* kb  = qb  + (size_t)2 * 8 * 4096 * 128;
  us* vtb = kb  + (size_t)2 * 8 * 4096 * 128;   // [2][8][128][4096]
  us* aob = vtb + (size_t)2 * 8 * 4096 * 128;   // 8192*1024
  float* ctab = (float*)(aob + (size_t)8192 * 1024); // [4096][64]
  float* stab = ctab + (size_t)4096 * 64;

  rope_table_kernel<<<4096, 64, 0, stream>>>(ctab, stab);
  cast_kernel<<<8192, 256, 0, stream>>>(x, xb, 8192 * 1024 / 4);
  cast_kernel<<<3072, 256, 0, stream>>>(w_qkv, wqb, 3072 * 1024 / 4);
  cast_kernel<<<1024, 256, 0, stream>>>(w_o, wob, 1024 * 1024 / 4);
  qkv_rope_kernel<<<dim3(64, 24), 256, 0, stream>>>(xb, wqb, ctab, stab, qb, kb, vtb);
  flash_kernel<<<dim3(64, 8, 2), 256, 0, stream>>>(qb, kb, vtb, aob);
  out_proj_kernel<<<dim3(64, 8), 256, 0, stream>>>(aob, wob, out);
}